// Round 1
// baseline (488.993 us; speedup 1.0000x reference)
//
#include <hip/hip_runtime.h>

#define BB 512
#define TT 512
#define KK 128

__device__ __forceinline__ float wave_max64(float v) {
  #pragma unroll
  for (int off = 32; off; off >>= 1) v = fmaxf(v, __shfl_xor(v, off, 64));
  return v;
}
__device__ __forceinline__ float wave_sum64(float v) {
  #pragma unroll
  for (int off = 32; off; off >>= 1) v += __shfl_xor(v, off, 64);
  return v;
}

// One block per batch element. 128 threads (2 waves); thread j owns DP column j.
// Works in base-2 log domain: alpha2 = alpha/ln2, E2[i][j] = 2^(trans[i][j]/ln2).
// Step: new_alpha2[j] = log2(sum_i 2^(alpha2[i]-m) * E2[i][j]) + m + pot*INV_LN2.
// m is the LAGGED block max (from previous step) -> bounded exponents, one
// barrier per step (double-buffered e vector + wave-max slots).
__global__ __launch_bounds__(128, 1) void crf_fwd_kernel(
    const float* __restrict__ pot, const int* __restrict__ tags,
    const float* __restrict__ trans, float* __restrict__ out) {
  const float INV_LN2 = 1.4426950408889634f;
  const float LN2 = 0.6931471805599453f;
  const int b = blockIdx.x;
  const int j = threadIdx.x;   // 0..127
  const int lane = j & 63, wid = j >> 6;

  __shared__ float e_buf[2][KK];
  __shared__ float wmax[2][2];   // [wave][buf]
  __shared__ float wsum[2];
  __shared__ float wsc[2];

  // ---- sequence score: unary + binary (gathers, one-time) ----
  float sc = 0.f;
  #pragma unroll
  for (int r = 0; r < TT / KK; ++r) {
    int t = j + r * KK;
    int tg = tags[b * TT + t];
    sc += pot[((size_t)b * TT + t) * KK + tg];
    if (t + 1 < TT) {
      int tg1 = tags[b * TT + t + 1];
      sc += trans[tg * KK + tg1];
    }
  }
  sc = wave_sum64(sc);
  if (lane == 0) wsc[wid] = sc;

  // ---- exp2 transition column j into registers (statically indexed) ----
  float regE[KK];
  #pragma unroll
  for (int i = 0; i < KK; ++i)
    regE[i] = __builtin_amdgcn_exp2f(trans[i * KK + j] * INV_LN2);

  // ---- forward DP ----
  const float* pb = pot + (size_t)b * TT * KK;
  float alpha = pb[j] * INV_LN2;
  {
    float wm = wave_max64(alpha);
    if (lane == 0) wmax[wid][0] = wm;
  }
  __syncthreads();
  float m = fmaxf(wmax[0][0], wmax[1][0]);   // exact max of alpha_0
  const float score = wsc[0] + wsc[1];

  for (int t = 1; t < TT; ++t) {
    const int buf = t & 1;
    float pv = pb[t * KK + j];               // prefetch next potentials
    float e = __builtin_amdgcn_exp2f(alpha - m);
    e_buf[buf][j] = e;
    float wm2 = wave_max64(alpha);           // max of alpha_{t-1} (for NEXT step)
    if (lane == 0) wmax[wid][buf] = wm2;
    __syncthreads();
    float mn = fmaxf(wmax[0][buf], wmax[1][buf]);
    const float4* e4 = (const float4*)(&e_buf[buf][0]);
    float s0 = 0.f, s1 = 0.f, s2 = 0.f, s3 = 0.f;
    float s4 = 0.f, s5 = 0.f, s6 = 0.f, s7 = 0.f;
    #pragma unroll
    for (int q = 0; q < KK / 8; ++q) {
      float4 a = e4[2 * q];
      float4 c = e4[2 * q + 1];
      s0 = fmaf(a.x, regE[8 * q + 0], s0);
      s1 = fmaf(a.y, regE[8 * q + 1], s1);
      s2 = fmaf(a.z, regE[8 * q + 2], s2);
      s3 = fmaf(a.w, regE[8 * q + 3], s3);
      s4 = fmaf(c.x, regE[8 * q + 4], s4);
      s5 = fmaf(c.y, regE[8 * q + 5], s5);
      s6 = fmaf(c.z, regE[8 * q + 6], s6);
      s7 = fmaf(c.w, regE[8 * q + 7], s7);
    }
    float s = ((s0 + s1) + (s2 + s3)) + ((s4 + s5) + (s6 + s7));
    alpha = fmaf(pv, INV_LN2, __builtin_amdgcn_logf(s) + m);
    m = mn;                                  // lagged max for next step
  }

  // ---- final logsumexp over alpha + output ----
  {
    float wm3 = wave_max64(alpha);
    if (lane == 0) wmax[wid][0] = wm3;
  }
  __syncthreads();
  float M = fmaxf(wmax[0][0], wmax[1][0]);
  float ex = __builtin_amdgcn_exp2f(alpha - M);
  float ws = wave_sum64(ex);
  if (lane == 0) wsum[wid] = ws;
  __syncthreads();
  if (j == 0) {
    float log_norm = (M + __builtin_amdgcn_logf(wsum[0] + wsum[1])) * LN2;
    out[b] = score - log_norm;
  }
}

extern "C" void kernel_launch(void* const* d_in, const int* in_sizes, int n_in,
                              void* d_out, int out_size, void* d_ws, size_t ws_size,
                              hipStream_t stream) {
  const float* pot = (const float*)d_in[0];
  const int* tags = (const int*)d_in[1];
  const float* trans = (const float*)d_in[2];
  float* out = (float*)d_out;
  crf_fwd_kernel<<<BB, KK, 0, stream>>>(pot, tags, trans, out);
}

// Round 2
// 355.753 us; speedup vs baseline: 1.3745x; 1.3745x over previous
//
#include <hip/hip_runtime.h>

#define BB 512
#define TT 512
#define KK 128
#define HC 64   // half-column length per thread

// One block per batch element. 256 threads = 4 waves.
// tid -> (j = tid&127: output column, h = tid>>7: which half of the i-sum).
// Linear-domain scaled forward DP:
//   v_t[j] = 2^(alpha_t[j]/ln2 - M_t),  M_t uniform across block.
//   step:  s_j = sum_i v[i] * E2[i][j]   (E2 = 2^(trans/ln2), in registers)
//          v_new[j] = s_j * 2^(pot*c - d),  M += d,
//   d = float-exponent of the column-0 sum (uniform, no reduction needed).
__global__ __launch_bounds__(256, 2) void crf_fwd_kernel(
    const float* __restrict__ pot, const int* __restrict__ tags,
    const float* __restrict__ trans, float* __restrict__ out) {
  const float C = 1.4426950408889634f;    // 1/ln2
  const float LN2 = 0.6931471805599453f;
  const int b = blockIdx.x;
  const int tid = threadIdx.x;
  const int j = tid & 127;
  const int h = tid >> 7;
  const int lane = tid & 63;
  const int wid = tid >> 6;

  __shared__ float vbuf[2][KK];
  __shared__ float pbuf[2][KK];   // partial sums [h][j]
  __shared__ float red[8];

  const float* pb = pot + (size_t)b * TT * KK;

  // ---- sequence score (one-time gathers) ----
  float sc;
  {
    int t0 = tid, t1 = tid + 256;
    int tg0 = tags[b * TT + t0];
    int tg1 = tags[b * TT + t1];
    sc = pb[(size_t)t0 * KK + tg0] + pb[(size_t)t1 * KK + tg1];
    int tgn0 = tags[b * TT + t0 + 1];
    sc += trans[tg0 * KK + tgn0];
    if (t1 + 1 < TT) {
      int tgn1 = tags[b * TT + t1 + 1];
      sc += trans[tg1 * KK + tgn1];
    }
  }
  #pragma unroll
  for (int off = 32; off; off >>= 1) sc += __shfl_xor(sc, off, 64);
  if (lane == 0) red[wid] = sc;

  // ---- transition half-column -> 64 registers ----
  float E[HC];
  #pragma unroll
  for (int k = 0; k < HC; ++k)
    E[k] = __builtin_amdgcn_exp2f(trans[(h * HC + k) * KK + j] * C);

  // ---- init v_0 ----
  float M = 0.f;
  if (h == 0) vbuf[0][j] = __builtin_amdgcn_exp2f(pb[j] * C);
  __syncthreads();
  const float score = red[0] + red[1] + red[2] + red[3];

  // pot pipeline (2 deep)
  float pvA = pb[(size_t)1 * KK + j];
  float pvB = pb[(size_t)2 * KK + j];

  float vj = 0.f;
  for (int t = 1; t < TT; ++t) {
    const int cb = t & 1;
    const float4* vv = (const float4*)&vbuf[cb ^ 1][h * HC];
    float s0 = 0.f, s1 = 0.f, s2 = 0.f, s3 = 0.f;
    float s4 = 0.f, s5 = 0.f, s6 = 0.f, s7 = 0.f;
    #pragma unroll
    for (int q = 0; q < 8; ++q) {
      float4 a = vv[2 * q];
      float4 c4 = vv[2 * q + 1];
      s0 = fmaf(a.x,  E[8 * q + 0], s0);
      s1 = fmaf(a.y,  E[8 * q + 1], s1);
      s2 = fmaf(a.z,  E[8 * q + 2], s2);
      s3 = fmaf(a.w,  E[8 * q + 3], s3);
      s4 = fmaf(c4.x, E[8 * q + 4], s4);
      s5 = fmaf(c4.y, E[8 * q + 5], s5);
      s6 = fmaf(c4.z, E[8 * q + 6], s6);
      s7 = fmaf(c4.w, E[8 * q + 7], s7);
    }
    float p = ((s0 + s1) + (s2 + s3)) + ((s4 + s5) + (s6 + s7));
    pbuf[h][j] = p;
    int tn = t + 2; if (tn > TT - 1) tn = TT - 1;
    float pvN = pb[(size_t)tn * KK + j];      // prefetch pot[t+2]
    __syncthreads();                          // A: partials visible
    float pp0 = pbuf[0][j], pp1 = pbuf[1][j];
    float r0 = pbuf[0][0], r1 = pbuf[1][0];   // broadcast reference column
    float s = pp0 + pp1;
    float sref = r0 + r1;
    int d = (int)((__float_as_uint(sref) >> 23) & 0xFF) - 127;
    M += (float)d;
    float ex = __builtin_amdgcn_exp2f(fmaf(pvA, C, (float)(-d)));
    vj = s * ex;
    if (h == 0) vbuf[cb][j] = vj;
    pvA = pvB; pvB = pvN;
    __syncthreads();                          // B: v visible
  }

  // ---- final logsumexp: sum v over j (waves 0 and 1 hold all columns) ----
  float x = vj;
  #pragma unroll
  for (int off = 32; off; off >>= 1) x += __shfl_xor(x, off, 64);
  if (lane == 0 && wid < 2) red[4 + wid] = x;
  __syncthreads();
  if (tid == 0) {
    float S = red[4] + red[5];
    float logZ = (M + __builtin_amdgcn_logf(S)) * LN2;  // v_log_f32 = log2
    out[b] = score - logZ;
  }
}

extern "C" void kernel_launch(void* const* d_in, const int* in_sizes, int n_in,
                              void* d_out, int out_size, void* d_ws, size_t ws_size,
                              hipStream_t stream) {
  const float* pot = (const float*)d_in[0];
  const int* tags = (const int*)d_in[1];
  const float* trans = (const float*)d_in[2];
  float* out = (float*)d_out;
  crf_fwd_kernel<<<BB, 256, 0, stream>>>(pot, tags, trans, out);
}

// Round 3
// 212.235 us; speedup vs baseline: 2.3040x; 1.6762x over previous
//
#include <hip/hip_runtime.h>

#define BB 512
#define TT 512
#define KK 128

// DPP-based add of a lane-shuffled copy (VALU pipe, no LDS).
template <int CTRL>
__device__ __forceinline__ float dpp_add(float x) {
  int y = __builtin_amdgcn_update_dpp(0, __float_as_int(x), CTRL, 0xF, 0xF, true);
  return x + __int_as_float(y);
}
// Sum over 8 consecutive lanes (8-aligned groups): xor1, xor2, xor4(half-mirror).
__device__ __forceinline__ float bfly8(float x) {
  x = dpp_add<0xB1>(x);    // quad_perm(1,0,3,2)
  x = dpp_add<0x4E>(x);    // quad_perm(2,3,0,1)
  x = dpp_add<0x141>(x);   // row_half_mirror (lane ^ 7 within 8)
  return x;
}

// One block per batch element, 256 threads = 4 waves.
// tid = c*8 + kp : c in [0,32) owns columns 4c..4c+3; kp in [0,8) owns k-rows
// 16kp..16kp+15. Linear-domain scaled DP (base-2):
//   w_t[j] = 2^(alpha_t[j]/ln2 - M_t),  M_t = sum of per-step integer scales d.
//   step: s_j = sum_i w[i] * E2[i][j];  w_new[j] = s_j * 2^(pot*C - d);
//   d = float exponent of w_{t-1}[0] (lagged -> known at step start, uniform).
__global__ __launch_bounds__(256, 2) void crf_fwd_kernel(
    const float* __restrict__ pot, const int* __restrict__ tags,
    const float* __restrict__ trans, float* __restrict__ out) {
  const float C = 1.4426950408889634f;    // 1/ln2
  const float LN2 = 0.6931471805599453f;
  const int b = blockIdx.x;
  const int tid = threadIdx.x;
  const int kp = tid & 7;
  const int c = tid >> 3;
  const int lane = tid & 63;
  const int wid = tid >> 6;

  __shared__ alignas(16) float vbuf[2][KK];
  __shared__ int dbuf[2];
  __shared__ float red[8];

  const float* pb = pot + (size_t)b * TT * KK;

  // ---- sequence score (one-time gathers) ----
  float sc;
  {
    int t0 = tid, t1 = tid + 256;
    int tg0 = tags[b * TT + t0];
    int tg1 = tags[b * TT + t1];
    sc = pb[(size_t)t0 * KK + tg0] + pb[(size_t)t1 * KK + tg1];
    int tgn0 = tags[b * TT + t0 + 1];
    sc += trans[tg0 * KK + tgn0];
    if (t1 + 1 < TT) sc += trans[tg1 * KK + tags[b * TT + t1 + 1]];
  }
  #pragma unroll
  for (int off = 32; off; off >>= 1) sc += __shfl_xor(sc, off, 64);
  if (lane == 0) red[wid] = sc;

  // ---- E2 tile -> 64 registers: Ec[k] = exp2(trans[16kp+k][4c..4c+3] * C) ----
  float4 Ec[16];
  #pragma unroll
  for (int k = 0; k < 16; ++k) {
    float4 tr = *(const float4*)&trans[(size_t)(16 * kp + k) * KK + 4 * c];
    Ec[k].x = __builtin_amdgcn_exp2f(tr.x * C);
    Ec[k].y = __builtin_amdgcn_exp2f(tr.y * C);
    Ec[k].z = __builtin_amdgcn_exp2f(tr.z * C);
    Ec[k].w = __builtin_amdgcn_exp2f(tr.w * C);
  }

  // ---- init w_0 ----
  if (tid < KK) {
    float w0 = __builtin_amdgcn_exp2f(pb[tid] * C);
    vbuf[0][tid] = w0;
    if (tid == 0) dbuf[0] = (int)((__float_as_uint(w0) >> 23) & 0xFF) - 127;
  }
  __syncthreads();
  const float score = red[0] + red[1] + red[2] + red[3];

  const int colw = 4 * c + (kp & 3);      // column this lane writes (kp<4)
  float pvA = pb[(size_t)1 * KK + colw];
  float pvB = pb[(size_t)2 * KK + colw];
  float M = 0.f;

  for (int t = 1; t < TT; ++t) {
    const int cb = t & 1, p = cb ^ 1;
    const float4* vv = (const float4*)&vbuf[p][kp * 16];
    float4 w0 = vv[0], w1 = vv[1], w2 = vv[2], w3 = vv[3];
    int d = dbuf[p];
    float s0 = 0.f, s1 = 0.f, s2 = 0.f, s3 = 0.f;
    #define FMA4(wv, k)                      \
      s0 = fmaf(wv, Ec[k].x, s0);            \
      s1 = fmaf(wv, Ec[k].y, s1);            \
      s2 = fmaf(wv, Ec[k].z, s2);            \
      s3 = fmaf(wv, Ec[k].w, s3);
    FMA4(w0.x, 0)  FMA4(w0.y, 1)  FMA4(w0.z, 2)  FMA4(w0.w, 3)
    FMA4(w1.x, 4)  FMA4(w1.y, 5)  FMA4(w1.z, 6)  FMA4(w1.w, 7)
    FMA4(w2.x, 8)  FMA4(w2.y, 9)  FMA4(w2.z, 10) FMA4(w2.w, 11)
    FMA4(w3.x, 12) FMA4(w3.y, 13) FMA4(w3.z, 14) FMA4(w3.w, 15)
    #undef FMA4
    int tn = t + 2; if (tn > TT - 1) tn = TT - 1;
    float pvN = pb[(size_t)tn * KK + colw];   // prefetch pot[t+2]
    // reduce the 8 k-partials per column across the 8-lane group (VALU only)
    s0 = bfly8(s0); s1 = bfly8(s1); s2 = bfly8(s2); s3 = bfly8(s3);
    int kq = kp & 3;
    float ssel = s0;
    ssel = (kq == 1) ? s1 : ssel;
    ssel = (kq == 2) ? s2 : ssel;
    ssel = (kq == 3) ? s3 : ssel;
    float exc = __builtin_amdgcn_exp2f(fmaf(pvA, C, (float)(-d)));
    float vnew = ssel * exc;
    M += (float)d;
    if (kp < 4) vbuf[cb][colw] = vnew;
    if (tid == 0)
      dbuf[cb] = (int)((__float_as_uint(vnew) >> 23) & 0xFF) - 127;
    pvA = pvB; pvB = pvN;
    __syncthreads();
  }

  // ---- final logsumexp: sum w_T over columns ----
  const int fin = (TT - 1) & 1;
  float x = (tid < KK) ? vbuf[fin][tid] : 0.f;
  #pragma unroll
  for (int off = 32; off; off >>= 1) x += __shfl_xor(x, off, 64);
  if (lane == 0) red[4 + wid] = x;
  __syncthreads();
  if (tid == 0) {
    float S = red[4] + red[5] + red[6] + red[7];
    float logZ = (M + __builtin_amdgcn_logf(S)) * LN2;  // v_log_f32 = log2
    out[b] = score - logZ;
  }
}

extern "C" void kernel_launch(void* const* d_in, const int* in_sizes, int n_in,
                              void* d_out, int out_size, void* d_ws, size_t ws_size,
                              hipStream_t stream) {
  const float* pot = (const float*)d_in[0];
  const int* tags = (const int*)d_in[1];
  const float* trans = (const float*)d_in[2];
  float* out = (float*)d_out;
  crf_fwd_kernel<<<BB, 256, 0, stream>>>(pot, tags, trans, out);
}

// Round 4
// 203.657 us; speedup vs baseline: 2.4011x; 1.0421x over previous
//
#include <hip/hip_runtime.h>

#define BB 512
#define TT 512
#define KK 128

// DPP-based add of a lane-shuffled copy (VALU pipe, no LDS).
template <int CTRL>
__device__ __forceinline__ float dpp_add(float x) {
  int y = __builtin_amdgcn_update_dpp(0, __float_as_int(x), CTRL, 0xF, 0xF, true);
  return x + __int_as_float(y);
}
// Sum over 8 consecutive lanes (8-aligned groups): xor1, xor2, mirror-within-8.
__device__ __forceinline__ float bfly8(float x) {
  x = dpp_add<0xB1>(x);    // quad_perm(1,0,3,2)
  x = dpp_add<0x4E>(x);    // quad_perm(2,3,0,1)
  x = dpp_add<0x141>(x);   // row_half_mirror (lane ^ 7 within 8)
  return x;
}

// One block per batch element, 256 threads = 4 waves.
// tid = c*8 + kp : c in [0,32) owns columns 4c..4c+3; kp in [0,8) owns the
// 16 k-rows {4kp + 32q + r, q,r in [0,4)}  -> q-th float4 read of the w
// vector sits at byte kp*16 + q*128 = banks 4kp..4kp+3: the 8 kp-groups
// tile all 32 banks (conflict-free); the 8 c-groups broadcast (free).
// Linear-domain scaled DP (base-2):
//   w_t[j] = 2^(alpha_t[j]/ln2 - M_t),  M_t = sum of per-step integer scales.
//   step: s_j = sum_i w[i] * E2[i][j];  w_new[j] = s_j * 2^(pot*C - d);
//   d = float exponent of w_{t-1}[0] (lagged -> known at step start, uniform).
__global__ __launch_bounds__(256, 2) void crf_fwd_kernel(
    const float* __restrict__ pot, const int* __restrict__ tags,
    const float* __restrict__ trans, float* __restrict__ out) {
  const float C = 1.4426950408889634f;    // 1/ln2
  const float LN2 = 0.6931471805599453f;
  const int b = blockIdx.x;
  const int tid = threadIdx.x;
  const int kp = tid & 7;
  const int c = tid >> 3;
  const int lane = tid & 63;
  const int wid = tid >> 6;

  __shared__ alignas(16) float vbuf[2][KK];
  __shared__ int dbuf[2];
  __shared__ float red[8];

  const float* pb = pot + (size_t)b * TT * KK;

  // ---- sequence score (one-time gathers) ----
  float sc;
  {
    int t0 = tid, t1 = tid + 256;
    int tg0 = tags[b * TT + t0];
    int tg1 = tags[b * TT + t1];
    sc = pb[(size_t)t0 * KK + tg0] + pb[(size_t)t1 * KK + tg1];
    int tgn0 = tags[b * TT + t0 + 1];
    sc += trans[tg0 * KK + tgn0];
    if (t1 + 1 < TT) sc += trans[tg1 * KK + tags[b * TT + t1 + 1]];
  }
  #pragma unroll
  for (int off = 32; off; off >>= 1) sc += __shfl_xor(sc, off, 64);
  if (lane == 0) red[wid] = sc;

  // ---- E2 tile -> 64 registers, matching the bank-tiled row ownership:
  //      Ec[4q+r] = exp2(trans[4kp+32q+r][4c..4c+3] * C)
  float4 Ec[16];
  #pragma unroll
  for (int q = 0; q < 4; ++q) {
    #pragma unroll
    for (int r = 0; r < 4; ++r) {
      int row = 4 * kp + 32 * q + r;
      float4 tr = *(const float4*)&trans[(size_t)row * KK + 4 * c];
      Ec[4 * q + r].x = __builtin_amdgcn_exp2f(tr.x * C);
      Ec[4 * q + r].y = __builtin_amdgcn_exp2f(tr.y * C);
      Ec[4 * q + r].z = __builtin_amdgcn_exp2f(tr.z * C);
      Ec[4 * q + r].w = __builtin_amdgcn_exp2f(tr.w * C);
    }
  }

  // ---- init w_0 ----
  if (tid < KK) {
    float w0 = __builtin_amdgcn_exp2f(pb[tid] * C);
    vbuf[0][tid] = w0;
    if (tid == 0) dbuf[0] = (int)((__float_as_uint(w0) >> 23) & 0xFF) - 127;
  }
  __syncthreads();
  const float score = red[0] + red[1] + red[2] + red[3];

  const int colw = 4 * c + (kp & 3);      // column this lane writes (kp<4)
  float pvA = pb[(size_t)1 * KK + colw];
  float pvB = pb[(size_t)2 * KK + colw];
  float M = 0.f;

  for (int t = 1; t < TT; ++t) {
    const int cb = t & 1, p = cb ^ 1;
    // q-th read: float4 at vbuf[p] + kp*4 + 32q  (banks 4kp..4kp+3)
    const float4* vv = (const float4*)&vbuf[p][kp * 4];
    float4 w0 = vv[0], w1 = vv[8], w2 = vv[16], w3 = vv[24];
    int d = dbuf[p];
    float s0 = 0.f, s1 = 0.f, s2 = 0.f, s3 = 0.f;
    #define FMA4(wv, k)                      \
      s0 = fmaf(wv, Ec[k].x, s0);            \
      s1 = fmaf(wv, Ec[k].y, s1);            \
      s2 = fmaf(wv, Ec[k].z, s2);            \
      s3 = fmaf(wv, Ec[k].w, s3);
    FMA4(w0.x, 0)  FMA4(w0.y, 1)  FMA4(w0.z, 2)  FMA4(w0.w, 3)
    FMA4(w1.x, 4)  FMA4(w1.y, 5)  FMA4(w1.z, 6)  FMA4(w1.w, 7)
    FMA4(w2.x, 8)  FMA4(w2.y, 9)  FMA4(w2.z, 10) FMA4(w2.w, 11)
    FMA4(w3.x, 12) FMA4(w3.y, 13) FMA4(w3.z, 14) FMA4(w3.w, 15)
    #undef FMA4
    int tn = t + 2; if (tn > TT - 1) tn = TT - 1;
    float pvN = pb[(size_t)tn * KK + colw];   // prefetch pot[t+2]
    // reduce the 8 k-partials per column across the 8-lane group (VALU only)
    s0 = bfly8(s0); s1 = bfly8(s1); s2 = bfly8(s2); s3 = bfly8(s3);
    int kq = kp & 3;
    float ssel = s0;
    ssel = (kq == 1) ? s1 : ssel;
    ssel = (kq == 2) ? s2 : ssel;
    ssel = (kq == 3) ? s3 : ssel;
    float exc = __builtin_amdgcn_exp2f(fmaf(pvA, C, (float)(-d)));
    float vnew = ssel * exc;
    M += (float)d;
    if (kp < 4) vbuf[cb][colw] = vnew;
    if (tid == 0)
      dbuf[cb] = (int)((__float_as_uint(vnew) >> 23) & 0xFF) - 127;
    pvA = pvB; pvB = pvN;
    __syncthreads();
  }

  // ---- final logsumexp: sum w_T over columns ----
  const int fin = (TT - 1) & 1;
  float x = (tid < KK) ? vbuf[fin][tid] : 0.f;
  #pragma unroll
  for (int off = 32; off; off >>= 1) x += __shfl_xor(x, off, 64);
  if (lane == 0) red[4 + wid] = x;
  __syncthreads();
  if (tid == 0) {
    float S = red[4] + red[5] + red[6] + red[7];
    float logZ = (M + __builtin_amdgcn_logf(S)) * LN2;  // v_log_f32 = log2
    out[b] = score - logZ;
  }
}

extern "C" void kernel_launch(void* const* d_in, const int* in_sizes, int n_in,
                              void* d_out, int out_size, void* d_ws, size_t ws_size,
                              hipStream_t stream) {
  const float* pot = (const float*)d_in[0];
  const int* tags = (const int*)d_in[1];
  const float* trans = (const float*)d_in[2];
  float* out = (float*)d_out;
  crf_fwd_kernel<<<BB, 256, 0, stream>>>(pot, tags, trans, out);
}

// Round 5
// 165.116 us; speedup vs baseline: 2.9615x; 1.2334x over previous
//
#include <hip/hip_runtime.h>

#define BB 512
#define TT 512
#define KK 128

typedef __attribute__((ext_vector_type(8))) short short8;   // 8 x bf16 bits
typedef __attribute__((ext_vector_type(4))) float f32x4;

// f32 -> bf16 bits, round-to-nearest-even (values are finite positives here)
__device__ __forceinline__ unsigned short f2bf(float f) {
  unsigned u = __float_as_uint(f);
  unsigned r = ((u >> 16) & 1u) + 0x7fffu;
  return (unsigned short)((u + r) >> 16);
}

// One block per batch element, 256 threads = 4 waves; wave w owns output
// columns [32w, 32w+32) as two 16-col MFMA tiles.
// Linear-domain scaled DP (base-2), same scheme as verified R4:
//   w_t[j] = 2^(alpha_t[j]/ln2 - M_t);  step: s = w . E2 (bf16 MFMA, fp32 acc),
//   w_new[j] = s_j * 2^(pot*C - d),  d = exponent of w_{t-1}[0] (lagged).
// A-operand: same 8-bf16 k-chunk broadcast to all 16 lanes of each lane-group
// -> all 16 MFMA rows compute the identical matvec (row-layout immune).
__global__ __launch_bounds__(256, 2) void crf_fwd_kernel(
    const float* __restrict__ pot, const int* __restrict__ tags,
    const float* __restrict__ trans, float* __restrict__ out) {
  const float C = 1.4426950408889634f;    // 1/ln2
  const float LN2 = 0.6931471805599453f;
  const int b = blockIdx.x;
  const int tid = threadIdx.x;
  const int lane = tid & 63;
  const int wid = tid >> 6;
  const int lg = lane >> 4;      // k-chunk group 0..3
  const int lc = lane & 15;      // column within tile

  __shared__ unsigned short wbuf[2][KK];  // scaled w, bf16
  __shared__ int dbuf[2];
  __shared__ float red[8];

  const float* pb = pot + (size_t)b * TT * KK;

  // ---- sequence score (one-time gathers) ----
  float sc;
  {
    int t0 = tid, t1 = tid + 256;
    int tg0 = tags[b * TT + t0];
    int tg1 = tags[b * TT + t1];
    sc = pb[(size_t)t0 * KK + tg0] + pb[(size_t)t1 * KK + tg1];
    sc += trans[tg0 * KK + tags[b * TT + t0 + 1]];
    if (t1 + 1 < TT) sc += trans[tg1 * KK + tags[b * TT + t1 + 1]];
  }
  #pragma unroll
  for (int off = 32; off; off >>= 1) sc += __shfl_xor(sc, off, 64);
  if (lane == 0) red[wid] = sc;

  // ---- constant B fragments: B[k=32q+8lg+e][j=16c+lc] = bf16(2^(trans*C)) ----
  short8 B0[4], B1[4];
  const int c0 = 2 * wid, c1 = 2 * wid + 1;
  #pragma unroll
  for (int q = 0; q < 4; ++q) {
    #pragma unroll
    for (int e = 0; e < 8; ++e) {
      int k = 32 * q + 8 * lg + e;
      B0[q][e] = (short)f2bf(__builtin_amdgcn_exp2f(trans[k * KK + 16 * c0 + lc] * C));
      B1[q][e] = (short)f2bf(__builtin_amdgcn_exp2f(trans[k * KK + 16 * c1 + lc] * C));
    }
  }

  // ---- init w_0 ----
  if (tid < KK) {
    float w0 = __builtin_amdgcn_exp2f(pb[tid] * C);
    wbuf[0][tid] = f2bf(w0);
    if (tid == 0) dbuf[0] = (int)((__float_as_uint(w0) >> 23) & 0xFF) - 127;
  }
  __syncthreads();
  const float score = red[0] + red[1] + red[2] + red[3];

  const int j0 = 32 * wid + lc, j1 = j0 + 16;
  float pvA0 = pb[(size_t)1 * KK + j0], pvA1 = pb[(size_t)1 * KK + j1];
  float pvB0 = pb[(size_t)2 * KK + j0], pvB1 = pb[(size_t)2 * KK + j1];
  float M = 0.f;
  float v0 = 0.f, v1 = 0.f;

  for (int t = 1; t < TT; ++t) {
    const int cb = t & 1, p = cb ^ 1;
    // A fragments: 16B broadcast reads (same addr within each 16-lane group)
    const unsigned short* wp = &wbuf[p][8 * lg];
    short8 A0 = *(const short8*)(wp);
    short8 A1 = *(const short8*)(wp + 32);
    short8 A2 = *(const short8*)(wp + 64);
    short8 A3 = *(const short8*)(wp + 96);
    int d = dbuf[p];
    int tn = t + 2; if (tn > TT - 1) tn = TT - 1;
    float pvN0 = pb[(size_t)tn * KK + j0];      // prefetch pot[t+2]
    float pvN1 = pb[(size_t)tn * KK + j1];
    f32x4 acc0 = {0.f, 0.f, 0.f, 0.f}, acc1 = {0.f, 0.f, 0.f, 0.f};
    __builtin_amdgcn_s_setprio(1);
    acc0 = __builtin_amdgcn_mfma_f32_16x16x32_bf16(A0, B0[0], acc0, 0, 0, 0);
    acc1 = __builtin_amdgcn_mfma_f32_16x16x32_bf16(A0, B1[0], acc1, 0, 0, 0);
    acc0 = __builtin_amdgcn_mfma_f32_16x16x32_bf16(A1, B0[1], acc0, 0, 0, 0);
    acc1 = __builtin_amdgcn_mfma_f32_16x16x32_bf16(A1, B1[1], acc1, 0, 0, 0);
    acc0 = __builtin_amdgcn_mfma_f32_16x16x32_bf16(A2, B0[2], acc0, 0, 0, 0);
    acc1 = __builtin_amdgcn_mfma_f32_16x16x32_bf16(A2, B1[2], acc1, 0, 0, 0);
    acc0 = __builtin_amdgcn_mfma_f32_16x16x32_bf16(A3, B0[3], acc0, 0, 0, 0);
    acc1 = __builtin_amdgcn_mfma_f32_16x16x32_bf16(A3, B1[3], acc1, 0, 0, 0);
    __builtin_amdgcn_s_setprio(0);
    // every lane's acc[0] = S[tile_col = lc] (rows identical by construction)
    float exc0 = __builtin_amdgcn_exp2f(fmaf(pvA0, C, (float)(-d)));
    float exc1 = __builtin_amdgcn_exp2f(fmaf(pvA1, C, (float)(-d)));
    v0 = acc0[0] * exc0;
    v1 = acc1[0] * exc1;
    M += (float)d;
    if (lane < 16) {
      wbuf[cb][j0] = f2bf(v0);
      wbuf[cb][j1] = f2bf(v1);
    }
    if (tid == 0)
      dbuf[cb] = (int)((__float_as_uint(v0) >> 23) & 0xFF) - 127;
    pvA0 = pvB0; pvA1 = pvB1; pvB0 = pvN0; pvB1 = pvN1;
    __syncthreads();
  }

  // ---- final logsumexp: sum w_T over all columns (f32 values in regs) ----
  float x = (lane < 16) ? (v0 + v1) : 0.f;
  #pragma unroll
  for (int off = 32; off; off >>= 1) x += __shfl_xor(x, off, 64);
  if (lane == 0) red[4 + wid] = x;
  __syncthreads();
  if (tid == 0) {
    float S = red[4] + red[5] + red[6] + red[7];
    float logZ = (M + __builtin_amdgcn_logf(S)) * LN2;  // v_log_f32 = log2
    out[b] = score - logZ;
  }
}

extern "C" void kernel_launch(void* const* d_in, const int* in_sizes, int n_in,
                              void* d_out, int out_size, void* d_ws, size_t ws_size,
                              hipStream_t stream) {
  const float* pot = (const float*)d_in[0];
  const int* tags = (const int*)d_in[1];
  const float* trans = (const float*)d_in[2];
  float* out = (float*)d_out;
  crf_fwd_kernel<<<BB, 256, 0, stream>>>(pot, tags, trans, out);
}

// Round 6
// 142.045 us; speedup vs baseline: 3.4425x; 1.1624x over previous
//
#include <hip/hip_runtime.h>

#define BB 512
#define TT 512
#define KK 128

typedef __attribute__((ext_vector_type(8))) short short8;   // 8 x bf16 bits
typedef __attribute__((ext_vector_type(4))) float f32x4;

// f32 -> bf16 bits, round-to-nearest-even (finite values)
__device__ __forceinline__ unsigned short f2bf(float f) {
  unsigned u = __float_as_uint(f);
  unsigned r = ((u >> 16) & 1u) + 0x7fffu;
  return (unsigned short)((u + r) >> 16);
}
__device__ __forceinline__ float bf2f(unsigned short h) {
  return __uint_as_float(((unsigned)h) << 16);
}
__device__ __forceinline__ int fexpo(float f) {
  return (int)((__float_as_uint(f) >> 23) & 0xFF) - 127;
}

// One block per batch element, 512 threads = 8 waves.
// Waves 0-3: FORWARD half  w_t = u_t . (E^T w_{t-1}),  t = 1..256  (256 steps)
// Waves 4-7: BACKWARD half y_{t-1} = u_{t-1} . (E y_t), t = 511..257 (255 steps)
//   where y_t ~ u_t . beta_t (scaled);  Z = beta_256^T w_256 -> dot at the meet.
// Both maintain scaled vectors (bf16 in LDS) with lagged power-of-2 rescale:
//   stored_new = (matvec) * 2^(pot*C - d),  d = exponent of previous stored[0],
//   M += d each step;  true value = stored * 2^M.
// Matvec via row-replicated 16x16x32 bf16 MFMA (A chunk broadcast to all rows);
// two 2-deep accumulator chains per output tile (shorter dep chain than 4-deep).
__global__ __launch_bounds__(512, 2) void crf_fwd_kernel(
    const float* __restrict__ pot, const int* __restrict__ tags,
    const float* __restrict__ trans, float* __restrict__ out) {
  const float C = 1.4426950408889634f;    // 1/ln2
  const float LN2 = 0.6931471805599453f;
  const int b = blockIdx.x;
  const int tid = threadIdx.x;            // 0..511
  const int lane = tid & 63;
  const int wid = tid >> 6;               // 0..7
  const int grp = wid >> 2;               // 0 = fwd, 1 = bwd
  const int wq = wid & 3;                 // column quarter within group
  const int lg = lane >> 4;               // k-chunk group 0..3
  const int lc = lane & 15;               // column within 16-tile

  __shared__ alignas(16) unsigned short buf[2][2][KK];  // [grp][parity][j]
  __shared__ int dbuf[2][2];
  __shared__ float red[12];

  const float* pb = pot + (size_t)b * TT * KK;

  // ---- sequence score: thread tid handles time-step tid ----
  float sc;
  {
    int tg0 = tags[b * TT + tid];
    sc = pb[(size_t)tid * KK + tg0];
    if (tid + 1 < TT) sc += trans[tg0 * KK + tags[b * TT + tid + 1]];
  }
  #pragma unroll
  for (int off = 32; off; off >>= 1) sc += __shfl_xor(sc, off, 64);
  if (lane == 0) red[wid] = sc;

  // ---- constant B fragments (fwd: E[k][j]; bwd: E[j][k] i.e. transposed) ----
  short8 B0[4], B1[4];
  const int c0 = 2 * wq, c1 = 2 * wq + 1;
  #pragma unroll
  for (int q = 0; q < 4; ++q) {
    #pragma unroll
    for (int e = 0; e < 8; ++e) {
      int k = 32 * q + 8 * lg + e;
      int ja = 16 * c0 + lc, jb = 16 * c1 + lc;
      float t0 = (grp == 0) ? trans[k * KK + ja] : trans[ja * KK + k];
      float t1 = (grp == 0) ? trans[k * KK + jb] : trans[jb * KK + k];
      B0[q][e] = (short)f2bf(__builtin_amdgcn_exp2f(t0 * C));
      B1[q][e] = (short)f2bf(__builtin_amdgcn_exp2f(t1 * C));
    }
  }

  // ---- init: fwd buf[0][0] = u_0;  bwd buf[1][0] = u_511 ----
  if (tid < KK) {
    float w0 = __builtin_amdgcn_exp2f(pb[tid] * C);
    buf[0][0][tid] = f2bf(w0);
    if (tid == 0) dbuf[0][0] = fexpo(w0);
  } else if (tid >= 256 && tid < 256 + KK) {
    int j = tid - 256;
    float y0 = __builtin_amdgcn_exp2f(pb[(size_t)(TT - 1) * KK + j] * C);
    buf[1][0][j] = f2bf(y0);
    if (j == 0) dbuf[1][0] = fexpo(y0);
  }
  __syncthreads();
  const float score = red[0] + red[1] + red[2] + red[3] +
                      red[4] + red[5] + red[6] + red[7];

  // pot row sequence: fwd rows 1,2,...  bwd rows 510,509,...
  const int r0 = grp ? (TT - 2) : 1;
  const int st = grp ? -1 : 1;
  const int j0 = 32 * wq + lc, j1 = j0 + 16;
  float pvA0 = pb[(size_t)r0 * KK + j0];
  float pvA1 = pb[(size_t)r0 * KK + j1];
  float pvB0 = pb[(size_t)(r0 + st) * KK + j0];
  float pvB1 = pb[(size_t)(r0 + st) * KK + j1];
  float M = 0.f;

  for (int it = 0; it < 256; ++it) {
    const int p = it & 1, w = p ^ 1;
    const unsigned short* wp = &buf[grp][p][8 * lg];
    short8 A0 = *(const short8*)(wp);
    short8 A1 = *(const short8*)(wp + 32);
    short8 A2 = *(const short8*)(wp + 64);
    short8 A3 = *(const short8*)(wp + 96);
    int d = dbuf[grp][p];
    int rn = r0 + st * (it + 2);                 // prefetch pot 2 ahead
    float pvN0 = pb[(size_t)rn * KK + j0];
    float pvN1 = pb[(size_t)rn * KK + j1];
    f32x4 z = {0.f, 0.f, 0.f, 0.f};
    f32x4 aP0, aQ0, aP1, aQ1;
    __builtin_amdgcn_s_setprio(1);
    aP0 = __builtin_amdgcn_mfma_f32_16x16x32_bf16(A0, B0[0], z, 0, 0, 0);
    aQ0 = __builtin_amdgcn_mfma_f32_16x16x32_bf16(A2, B0[2], z, 0, 0, 0);
    aP1 = __builtin_amdgcn_mfma_f32_16x16x32_bf16(A0, B1[0], z, 0, 0, 0);
    aQ1 = __builtin_amdgcn_mfma_f32_16x16x32_bf16(A2, B1[2], z, 0, 0, 0);
    aP0 = __builtin_amdgcn_mfma_f32_16x16x32_bf16(A1, B0[1], aP0, 0, 0, 0);
    aQ0 = __builtin_amdgcn_mfma_f32_16x16x32_bf16(A3, B0[3], aQ0, 0, 0, 0);
    aP1 = __builtin_amdgcn_mfma_f32_16x16x32_bf16(A1, B1[1], aP1, 0, 0, 0);
    aQ1 = __builtin_amdgcn_mfma_f32_16x16x32_bf16(A3, B1[3], aQ1, 0, 0, 0);
    __builtin_amdgcn_s_setprio(0);
    float z0 = aP0[0] + aQ0[0];
    float z1 = aP1[0] + aQ1[0];
    // bwd's LAST update (it==254) must not multiply u (meet at t=256)
    const bool lastB = (grp == 1) && (it == 254);
    const bool active = (grp == 0) || (it < 255);
    float pe0 = lastB ? 0.f : pvA0;
    float pe1 = lastB ? 0.f : pvA1;
    float exc0 = __builtin_amdgcn_exp2f(fmaf(pe0, C, (float)(-d)));
    float exc1 = __builtin_amdgcn_exp2f(fmaf(pe1, C, (float)(-d)));
    float v0 = z0 * exc0;
    float v1 = z1 * exc1;
    if (active) {
      M += (float)d;
      if (lane < 16) {
        buf[grp][w][j0] = f2bf(v0);
        buf[grp][w][j1] = f2bf(v1);
      }
      if (lane == 0 && wq == 0) dbuf[grp][w] = fexpo(v0);
    }
    pvA0 = pvB0; pvA1 = pvB1; pvB0 = pvN0; pvB1 = pvN1;
    __syncthreads();
  }

  // ---- meet: Z = 2^(Mf+Mb) * sum_j wF[j] * yB[j] ----
  // final buffers: fwd wrote parity 0 at it=255; bwd wrote parity 1 at it=254.
  if (lane == 0 && wq == 0) red[10 + grp] = M;   // Mf -> red[10], Mb -> red[11]
  if (tid < KK) {
    float prod = bf2f(buf[0][0][tid]) * bf2f(buf[1][1][tid]);
    #pragma unroll
    for (int off = 32; off; off >>= 1) prod += __shfl_xor(prod, off, 64);
    if (lane == 0) red[8 + wid] = prod;          // wid 0,1
  }
  __syncthreads();
  if (tid == 0) {
    float S = red[8] + red[9];
    float logZ = (red[10] + red[11] + __builtin_amdgcn_logf(S)) * LN2;
    out[b] = score - logZ;
  }
}

extern "C" void kernel_launch(void* const* d_in, const int* in_sizes, int n_in,
                              void* d_out, int out_size, void* d_ws, size_t ws_size,
                              hipStream_t stream) {
  const float* pot = (const float*)d_in[0];
  const int* tags = (const int*)d_in[1];
  const float* trans = (const float*)d_in[2];
  float* out = (float*)d_out;
  crf_fwd_kernel<<<BB, 512, 0, stream>>>(pot, tags, trans, out);
}

// Round 7
// 140.624 us; speedup vs baseline: 3.4773x; 1.0101x over previous
//
#include <hip/hip_runtime.h>

#define BB 512
#define TT 512
#define KK 128

typedef __attribute__((ext_vector_type(8))) short short8;   // 8 x bf16 bits
typedef __attribute__((ext_vector_type(4))) float f32x4;

// f32 -> bf16 bits, round-to-nearest-even (finite values)
__device__ __forceinline__ unsigned short f2bf(float f) {
  unsigned u = __float_as_uint(f);
  unsigned r = ((u >> 16) & 1u) + 0x7fffu;
  return (unsigned short)((u + r) >> 16);
}
__device__ __forceinline__ float bf2f(unsigned short h) {
  return __uint_as_float(((unsigned)h) << 16);
}
__device__ __forceinline__ int fexpo(float f) {
  return (int)((__float_as_uint(f) >> 23) & 0xFF) - 127;
}

// Non-draining barrier: drain LDS ops (cross-wave ds_write->ds_read handoff)
// but leave global prefetch loads IN FLIGHT across the barrier.
// __syncthreads would emit s_waitcnt vmcnt(0) and kill the pot pipeline.
__device__ __forceinline__ void lds_barrier() {
  asm volatile("s_waitcnt lgkmcnt(0)\n\ts_barrier" ::: "memory");
}

// One block per batch element, 512 threads = 8 waves.
// Waves 0-3: FORWARD half  w_t = u_t . (E^T w_{t-1}),  t = 1..256  (256 steps)
// Waves 4-7: BACKWARD half y_{t-1} = u_{t-1} . (E y_t), t = 511..257 (255 steps)
//   where y_t ~ u_t . beta_t (scaled);  Z = beta_256^T w_256 -> dot at the meet.
// Scaled vectors (bf16 in LDS), lagged power-of-2 rescale:
//   stored_new = (matvec) * 2^(pot*C - d),  d = exponent of previous stored[0],
//   M += d each step;  true value = stored * 2^M.
// Matvec via row-replicated 16x16x32 bf16 MFMA (A chunk broadcast to all rows);
// two 2-deep accumulator chains per output tile. pot prefetched 3 steps ahead,
// loads survive across the non-draining barrier (counted-vmcnt idiom).
__global__ __launch_bounds__(512, 2) void crf_fwd_kernel(
    const float* __restrict__ pot, const int* __restrict__ tags,
    const float* __restrict__ trans, float* __restrict__ out) {
  const float C = 1.4426950408889634f;    // 1/ln2
  const float LN2 = 0.6931471805599453f;
  const int b = blockIdx.x;
  const int tid = threadIdx.x;            // 0..511
  const int lane = tid & 63;
  const int wid = tid >> 6;               // 0..7
  const int grp = wid >> 2;               // 0 = fwd, 1 = bwd
  const int wq = wid & 3;                 // column quarter within group
  const int lg = lane >> 4;               // k-chunk group 0..3
  const int lc = lane & 15;               // column within 16-tile

  __shared__ alignas(16) unsigned short buf[2][2][KK];  // [grp][parity][j]
  __shared__ int dbuf[2][2];
  __shared__ float red[12];

  const float* pb = pot + (size_t)b * TT * KK;

  // ---- sequence score: thread tid handles time-step tid ----
  float sc;
  {
    int tg0 = tags[b * TT + tid];
    sc = pb[(size_t)tid * KK + tg0];
    if (tid + 1 < TT) sc += trans[tg0 * KK + tags[b * TT + tid + 1]];
  }
  #pragma unroll
  for (int off = 32; off; off >>= 1) sc += __shfl_xor(sc, off, 64);
  if (lane == 0) red[wid] = sc;

  // ---- constant B fragments (fwd: E[k][j]; bwd: E[j][k] i.e. transposed) ----
  short8 B0[4], B1[4];
  const int c0 = 2 * wq, c1 = 2 * wq + 1;
  #pragma unroll
  for (int q = 0; q < 4; ++q) {
    #pragma unroll
    for (int e = 0; e < 8; ++e) {
      int k = 32 * q + 8 * lg + e;
      int ja = 16 * c0 + lc, jb = 16 * c1 + lc;
      float t0 = (grp == 0) ? trans[k * KK + ja] : trans[ja * KK + k];
      float t1 = (grp == 0) ? trans[k * KK + jb] : trans[jb * KK + k];
      B0[q][e] = (short)f2bf(__builtin_amdgcn_exp2f(t0 * C));
      B1[q][e] = (short)f2bf(__builtin_amdgcn_exp2f(t1 * C));
    }
  }

  // ---- init: fwd buf[0][0] = u_0;  bwd buf[1][0] = u_511 ----
  if (tid < KK) {
    float w0 = __builtin_amdgcn_exp2f(pb[tid] * C);
    buf[0][0][tid] = f2bf(w0);
    if (tid == 0) dbuf[0][0] = fexpo(w0);
  } else if (tid >= 256 && tid < 256 + KK) {
    int j = tid - 256;
    float y0 = __builtin_amdgcn_exp2f(pb[(size_t)(TT - 1) * KK + j] * C);
    buf[1][0][j] = f2bf(y0);
    if (j == 0) dbuf[1][0] = fexpo(y0);
  }
  __syncthreads();
  const float score = red[0] + red[1] + red[2] + red[3] +
                      red[4] + red[5] + red[6] + red[7];

  // pot row sequence: fwd rows 1,2,...  bwd rows 510,509,... ; 3-deep pipeline
  const int r0 = grp ? (TT - 2) : 1;
  const int st = grp ? -1 : 1;
  const int j0 = 32 * wq + lc, j1 = j0 + 16;
  float pvA0 = pb[(size_t)r0 * KK + j0];
  float pvA1 = pb[(size_t)r0 * KK + j1];
  float pvB0 = pb[(size_t)(r0 + st) * KK + j0];
  float pvB1 = pb[(size_t)(r0 + st) * KK + j1];
  float pvC0 = pb[(size_t)(r0 + 2 * st) * KK + j0];
  float pvC1 = pb[(size_t)(r0 + 2 * st) * KK + j1];
  float M = 0.f;

  for (int it = 0; it < 256; ++it) {
    const int p = it & 1, w = p ^ 1;
    const unsigned short* wp = &buf[grp][p][8 * lg];
    short8 A0 = *(const short8*)(wp);
    short8 A1 = *(const short8*)(wp + 32);
    short8 A2 = *(const short8*)(wp + 64);
    short8 A3 = *(const short8*)(wp + 96);
    int d = dbuf[grp][p];
    int rn = r0 + st * (it + 3);                 // prefetch pot 3 ahead (in-bounds)
    float pvN0 = pb[(size_t)rn * KK + j0];
    float pvN1 = pb[(size_t)rn * KK + j1];
    f32x4 z = {0.f, 0.f, 0.f, 0.f};
    f32x4 aP0, aQ0, aP1, aQ1;
    __builtin_amdgcn_s_setprio(1);
    aP0 = __builtin_amdgcn_mfma_f32_16x16x32_bf16(A0, B0[0], z, 0, 0, 0);
    aQ0 = __builtin_amdgcn_mfma_f32_16x16x32_bf16(A2, B0[2], z, 0, 0, 0);
    aP1 = __builtin_amdgcn_mfma_f32_16x16x32_bf16(A0, B1[0], z, 0, 0, 0);
    aQ1 = __builtin_amdgcn_mfma_f32_16x16x32_bf16(A2, B1[2], z, 0, 0, 0);
    aP0 = __builtin_amdgcn_mfma_f32_16x16x32_bf16(A1, B0[1], aP0, 0, 0, 0);
    aQ0 = __builtin_amdgcn_mfma_f32_16x16x32_bf16(A3, B0[3], aQ0, 0, 0, 0);
    aP1 = __builtin_amdgcn_mfma_f32_16x16x32_bf16(A1, B1[1], aP1, 0, 0, 0);
    aQ1 = __builtin_amdgcn_mfma_f32_16x16x32_bf16(A3, B1[3], aQ1, 0, 0, 0);
    __builtin_amdgcn_s_setprio(0);
    float z0 = aP0[0] + aQ0[0];
    float z1 = aP1[0] + aQ1[0];
    // bwd's LAST update (it==254) must not multiply u (meet at t=256)
    const bool lastB = (grp == 1) && (it == 254);
    const bool active = (grp == 0) || (it < 255);
    float pe0 = lastB ? 0.f : pvA0;
    float pe1 = lastB ? 0.f : pvA1;
    float exc0 = __builtin_amdgcn_exp2f(fmaf(pe0, C, (float)(-d)));
    float exc1 = __builtin_amdgcn_exp2f(fmaf(pe1, C, (float)(-d)));
    float v0 = z0 * exc0;
    float v1 = z1 * exc1;
    if (active) {
      M += (float)d;
      if (lane < 16) {
        buf[grp][w][j0] = f2bf(v0);
        buf[grp][w][j1] = f2bf(v1);
      }
      if (lane == 0 && wq == 0) dbuf[grp][w] = fexpo(v0);
    }
    pvA0 = pvB0; pvA1 = pvB1;
    pvB0 = pvC0; pvB1 = pvC1;
    pvC0 = pvN0; pvC1 = pvN1;
    lds_barrier();   // lgkmcnt(0)+s_barrier only; global loads stay in flight
  }

  // ---- meet: Z = 2^(Mf+Mb) * sum_j wF[j] * yB[j] ----
  // final buffers: fwd wrote parity 0 at it=255; bwd wrote parity 1 at it=254.
  if (lane == 0 && wq == 0) red[10 + grp] = M;   // Mf -> red[10], Mb -> red[11]
  if (tid < KK) {
    float prod = bf2f(buf[0][0][tid]) * bf2f(buf[1][1][tid]);
    #pragma unroll
    for (int off = 32; off; off >>= 1) prod += __shfl_xor(prod, off, 64);
    if (lane == 0) red[8 + wid] = prod;          // wid 0,1
  }
  __syncthreads();
  if (tid == 0) {
    float S = red[8] + red[9];
    float logZ = (red[10] + red[11] + __builtin_amdgcn_logf(S)) * LN2;
    out[b] = score - logZ;
  }
}

extern "C" void kernel_launch(void* const* d_in, const int* in_sizes, int n_in,
                              void* d_out, int out_size, void* d_ws, size_t ws_size,
                              hipStream_t stream) {
  const float* pot = (const float*)d_in[0];
  const int* tags = (const int*)d_in[1];
  const float* trans = (const float*)d_in[2];
  float* out = (float*)d_out;
  crf_fwd_kernel<<<BB, 512, 0, stream>>>(pot, tags, trans, out);
}